// Round 1
// 984.877 us; speedup vs baseline: 1.0347x; 1.0347x over previous
//
#include <hip/hip_runtime.h>

typedef unsigned short u16;
typedef unsigned int   u32;
typedef __attribute__((ext_vector_type(8))) short short8;
typedef __attribute__((ext_vector_type(4))) float f32x4;

#define NTOK 65536
#define IND  768
#define HID  512
#define CBD  256
#define CBS  512

// d_out layout (floats): recon[NTOK*IND], indices-as-float[NTOK], loss[1]
#define OUT_IDX_OFF   ((size_t)NTOK * IND)
#define OUT_LOSS_OFF  (OUT_IDX_OFF + NTOK)

// ws byte offsets (total 203,950,080 <= proven round-1 usage 203,950,084)
#define OFF_H      ((size_t)0)            // Hpack u32 [NTOK][HID]  = 134,217,728 B
#define OFF_Z      ((size_t)134217728)    // Zpack u32 [NTOK][CBD]  =  67,108,864 B
#define OFF_W1H    ((size_t)201326592)    // W1T hi u16 [HID][IND]
#define OFF_W1L    ((size_t)202113024)
#define OFF_W2H    ((size_t)202899456)    // W2T hi u16 [CBD][HID]
#define OFF_W2L    ((size_t)203161600)
#define OFF_CBH    ((size_t)203423744)    // CB  hi u16 [CBS][CBD]
#define OFF_CBL    ((size_t)203685888)
#define OFF_CSQ    ((size_t)203948032)    // c_sq f32 [CBS]
// aliases inside H region (H dead after GEMM2 consumes it; all writers below
// run after GEMM2 in stream order)
#define OFF_PART   ((size_t)0)            // partials float4 [NTOK][8]  = 8,388,608 B
#define OFF_TABLE  ((size_t)8388608)      // ReconTable f32 [CBS][IND]  = 1,572,864 B
#define OFF_ZSQ    ((size_t)9961472)      // zsq f32 [NTOK]             =   262,144 B
#define OFF_IDX    ((size_t)10223616)     // idx int [NTOK]
#define OFF_FLAGS  ((size_t)10485760)     // flag list int [NTOK]
#define OFF_CNT    ((size_t)10747904)     // [0]=flag_count int, [4]=accum float

__device__ __forceinline__ u16 f2bf(float f) {
    u32 u = __float_as_uint(f);
    return (u16)((u + 0x7fffu + ((u >> 16) & 1u)) >> 16);
}
__device__ __forceinline__ float bf2f(u16 h) {
    return __uint_as_float(((u32)h) << 16);
}

// ---------------------------------------------------------------------------
// codebook split + c_sq : one block per code
// ---------------------------------------------------------------------------
__global__ __launch_bounds__(256) void cbsplit(
    const float* __restrict__ cb, u16* __restrict__ hi, u16* __restrict__ lo,
    float* __restrict__ csq)
{
    int c = blockIdx.x, t = threadIdx.x;
    float v = cb[(size_t)c * CBD + t];
    u16 h = f2bf(v); u16 l = f2bf(v - bf2f(h));
    hi[(size_t)c * CBD + t] = h; lo[(size_t)c * CBD + t] = l;
    __shared__ float red[256];
    red[t] = v * v; __syncthreads();
    for (int s = 128; s; s >>= 1) { if (t < s) red[t] += red[t + s]; __syncthreads(); }
    if (!t) csq[c] = red[0];
}

// ---------------------------------------------------------------------------
// weight transpose+split: W [K,N] fp32 -> WT hi/lo bf16 [N,K]. block per n.
// ---------------------------------------------------------------------------
__global__ __launch_bounds__(256) void wsplit(
    const float* __restrict__ W, u16* __restrict__ hi, u16* __restrict__ lo,
    int K, int N)
{
    int n = blockIdx.x;
    for (int k = threadIdx.x; k < K; k += 256) {
        float v = W[(size_t)k * N + n];
        u16 h = f2bf(v); u16 l = f2bf(v - bf2f(h));
        hi[(size_t)n * K + k] = h; lo[(size_t)n * K + k] = l;
    }
}

// ---------------------------------------------------------------------------
// bf16x3 MFMA GEMM: 128x128 tile, BK=32, 256 thr (4 waves), 4x4 16x16x32 frags
// AMODE 0: A fp32 [M,K] (convert in staging)   AMODE 1: A packed hi|lo u32 [M,K]
// EPI 0: relu(acc+bias) -> packed u32          EPI 1: acc+bias -> packed u32
// EPI 2: dist = bias[n] - 2*acc; per-row/wave-col top2 -> partials[row][bx*2+wcol]
// ---------------------------------------------------------------------------
template<int AMODE, int EPI>
__global__ __launch_bounds__(256, 2) void gemm3(
    const float* __restrict__ Af, const u32* __restrict__ Apk,
    const u16* __restrict__ Bhi, const u16* __restrict__ Blo,
    const float* __restrict__ bias,
    u32* __restrict__ Opk, float* __restrict__ Opart,
    int M, int N, int K)
{
    __shared__ u16 lds[4 * 128 * 40];         // 40 KB: Ahi, Alo, Bhi, Blo [128][40]
    u16* sAh = lds;
    u16* sAl = lds + 5120;
    u16* sBh = lds + 10240;
    u16* sBl = lds + 15360;
    const int tid  = threadIdx.x;
    const int m0 = blockIdx.y * 128, n0 = blockIdx.x * 128;
    const int w = tid >> 6, lane = tid & 63, quad = lane >> 4, l15 = lane & 15;
    const int wm = (w & 1) * 64, wn = (w >> 1) * 64;

    f32x4 acc[4][4] = {};

    for (int k0 = 0; k0 < K; k0 += 32) {
        __syncthreads();
        if (AMODE == 0) {
            #pragma unroll
            for (int s = 0; s < 4; ++s) {
                int slot = tid + s * 256;
                int m = slot >> 3, kg = (slot & 7) << 2;
                float4 v = *(const float4*)(Af + (size_t)(m0 + m) * K + k0 + kg);
                u16 h0 = f2bf(v.x), h1 = f2bf(v.y), h2 = f2bf(v.z), h3 = f2bf(v.w);
                ushort4 hv = {h0, h1, h2, h3};
                ushort4 lv = {f2bf(v.x - bf2f(h0)), f2bf(v.y - bf2f(h1)),
                              f2bf(v.z - bf2f(h2)), f2bf(v.w - bf2f(h3))};
                *(ushort4*)&sAh[m * 40 + kg] = hv;
                *(ushort4*)&sAl[m * 40 + kg] = lv;
            }
        } else {
            #pragma unroll
            for (int s = 0; s < 4; ++s) {
                int slot = tid + s * 256;
                int m = slot >> 3, ke = (slot & 7) << 2;   // 4 elems per uint4
                uint4 u = *(const uint4*)(Apk + (size_t)(m0 + m) * K + k0 + ke);
                ushort4 hv = {(u16)(u.x & 0xffff), (u16)(u.y & 0xffff),
                              (u16)(u.z & 0xffff), (u16)(u.w & 0xffff)};
                ushort4 lv = {(u16)(u.x >> 16), (u16)(u.y >> 16),
                              (u16)(u.z >> 16), (u16)(u.w >> 16)};
                *(ushort4*)&sAh[m * 40 + ke] = hv;
                *(ushort4*)&sAl[m * 40 + ke] = lv;
            }
        }
        // B planes [N,K] bf16 -> LDS
        #pragma unroll
        for (int s = 0; s < 4; ++s) {
            int slot = tid + s * 256;                 // 1024 slots, 512 per plane
            int n = (slot & 511) >> 2, ku = slot & 3; // 8 elems per uint4
            const u16* src = (slot < 512) ? Bhi : Blo;
            u16* dst = (slot < 512) ? sBh : sBl;
            uint4 u = *(const uint4*)(src + (size_t)(n0 + n) * K + k0 + ku * 8);
            *(uint4*)&dst[n * 40 + ku * 8] = u;
        }
        __syncthreads();

        short8 ah[4], al[4], bh[4], bl[4];
        const int ko = quad * 8;
        #pragma unroll
        for (int i = 0; i < 4; ++i) {
            int ar = wm + i * 16 + l15;
            int br = wn + i * 16 + l15;
            ah[i] = *(const short8*)&sAh[ar * 40 + ko];
            al[i] = *(const short8*)&sAl[ar * 40 + ko];
            bh[i] = *(const short8*)&sBh[br * 40 + ko];
            bl[i] = *(const short8*)&sBl[br * 40 + ko];
        }
        #pragma unroll
        for (int i = 0; i < 4; ++i)
            #pragma unroll
            for (int j = 0; j < 4; ++j) {
                acc[i][j] = __builtin_amdgcn_mfma_f32_16x16x32_bf16(ah[i], bh[j], acc[i][j], 0, 0, 0);
                acc[i][j] = __builtin_amdgcn_mfma_f32_16x16x32_bf16(ah[i], bl[j], acc[i][j], 0, 0, 0);
                acc[i][j] = __builtin_amdgcn_mfma_f32_16x16x32_bf16(al[i], bh[j], acc[i][j], 0, 0, 0);
            }
    }

    // epilogue. C/D layout: col = n-tile + l15, row = m-tile + quad*4 + r
    if (EPI <= 1) {
        float bn[4];
        #pragma unroll
        for (int j = 0; j < 4; ++j) bn[j] = bias[n0 + wn + j * 16 + l15];
        #pragma unroll
        for (int i = 0; i < 4; ++i)
            #pragma unroll
            for (int r = 0; r < 4; ++r) {
                int row = m0 + wm + i * 16 + quad * 4 + r;
                #pragma unroll
                for (int j = 0; j < 4; ++j) {
                    float v = acc[i][j][r] + bn[j];
                    if (EPI == 0) v = fmaxf(v, 0.f);
                    u16 h = f2bf(v); u16 l = f2bf(v - bf2f(h));
                    Opk[(size_t)row * N + n0 + wn + j * 16 + l15] = (u32)h | ((u32)l << 16);
                }
            }
    } else {
        float cs[4]; int cidx[4];
        #pragma unroll
        for (int j = 0; j < 4; ++j) {
            cidx[j] = n0 + wn + j * 16 + l15;
            cs[j] = bias[cidx[j]];
        }
        const int nparts = gridDim.x * 2;
        const int pslot  = blockIdx.x * 2 + (w >> 1);   // distinct per wave-column!
        #pragma unroll
        for (int i = 0; i < 4; ++i)
            #pragma unroll
            for (int r = 0; r < 4; ++r) {
                int row = m0 + wm + i * 16 + quad * 4 + r;
                float d1 = 3.4e38f, d2 = 3.4e38f; int i1 = 0x7fffffff;
                #pragma unroll
                for (int j = 0; j < 4; ++j) {
                    float v = fmaf(-2.0f, acc[i][j][r], cs[j]);
                    if (v < d1) { d2 = d1; d1 = v; i1 = cidx[j]; }
                    else d2 = fminf(d2, v);
                }
                #pragma unroll
                for (int mm = 1; mm < 16; mm <<= 1) {
                    float od1 = __shfl_xor(d1, mm, 64);
                    float od2 = __shfl_xor(d2, mm, 64);
                    int   oi1 = __shfl_xor(i1, mm, 64);
                    if (od1 < d1 || (od1 == d1 && oi1 < i1)) { d2 = fminf(d1, od2); d1 = od1; i1 = oi1; }
                    else d2 = fminf(d2, od1);
                }
                if (l15 == 0) {
                    float4 o = {d1, d2, __int_as_float(i1), 0.f};
                    *(float4*)&Opart[((size_t)row * nparts + pslot) * 4] = o;
                }
            }
    }
}

// ---------------------------------------------------------------------------
// zsq from packed z
// ---------------------------------------------------------------------------
__global__ __launch_bounds__(256) void zsq_pk(
    const u32* __restrict__ Zpk, float* __restrict__ zsq)
{
    int tok = blockIdx.x * 4 + (threadIdx.x >> 6);
    int lane = threadIdx.x & 63;
    uint4 u = *(const uint4*)(Zpk + (size_t)tok * CBD + lane * 4);
    float z0 = bf2f((u16)(u.x & 0xffff)) + bf2f((u16)(u.x >> 16));
    float z1 = bf2f((u16)(u.y & 0xffff)) + bf2f((u16)(u.y >> 16));
    float z2 = bf2f((u16)(u.z & 0xffff)) + bf2f((u16)(u.z >> 16));
    float z3 = bf2f((u16)(u.w & 0xffff)) + bf2f((u16)(u.w >> 16));
    float s = z0 * z0 + z1 * z1 + z2 * z2 + z3 * z3;
    #pragma unroll
    for (int off = 32; off; off >>= 1) s += __shfl_down(s, off, 64);
    if (!lane) zsq[tok] = s;
}

// ---------------------------------------------------------------------------
// combine per-slot top2 partials (8 per token) -> idx, flags, commit sum
// ---------------------------------------------------------------------------
__global__ __launch_bounds__(256) void vq_reduce(
    const float* __restrict__ part, const float* __restrict__ zsq,
    float* __restrict__ out_idx, int* __restrict__ idx_i,
    int* __restrict__ cnt, float* __restrict__ accum, int* __restrict__ flags)
{
    int tok = blockIdx.x * 256 + threadIdx.x;
    float d1 = 3.4e38f, d2 = 3.4e38f; int i1 = 0x7fffffff;
    #pragma unroll
    for (int nb = 0; nb < 8; ++nb) {
        float4 p = *(const float4*)&part[((size_t)tok * 8 + nb) * 4];
        float pd1 = p.x, pd2 = p.y; int pi1 = __float_as_int(p.z);
        if (pd1 < d1 || (pd1 == d1 && pi1 < i1)) { d2 = fminf(d1, pd2); d1 = pd1; i1 = pi1; }
        else d2 = fminf(d2, pd1);
    }
    out_idx[tok] = (float)i1;
    idx_i[tok] = i1;
    if (d2 - d1 < 0.05f) {
        int p = atomicAdd(cnt, 1);
        if (p >= 0 && p < NTOK) flags[p] = tok;
    }
    float c = zsq[tok] + d1;      // ||z||^2 + c_sq - 2 dot = ||z - q||^2
    __shared__ float red[256];
    red[threadIdx.x] = c; __syncthreads();
    for (int s = 128; s; s >>= 1) { if (threadIdx.x < s) red[threadIdx.x] += red[threadIdx.x + s]; __syncthreads(); }
    if (!threadIdx.x) atomicAdd(accum, red[0]);
}

// ---------------------------------------------------------------------------
// exact fp32 recompute of argmin for near-tie tokens.
// Round-N rewrite: batch 8 tokens per block iteration so W1/W2/cb are read
// from L2 once per 8 tokens (was: once per token -> ~9 GB L2 traffic, 295us,
// 8% occupancy). Numerics per (token,output) are bitwise identical to the old
// kernel: same ascending-k single-accumulator chains, same float4 dot
// expression, same 64-lane butterfly order, same first-index tie-breaks.
// ---------------------------------------------------------------------------
__global__ __launch_bounds__(256) void fixup(
    const int* __restrict__ cnt, const int* __restrict__ flags,
    const float* __restrict__ x, const float* __restrict__ W1, const float* __restrict__ b1,
    const float* __restrict__ W2, const float* __restrict__ b2,
    const float* __restrict__ cb, const float* __restrict__ csq,
    int* __restrict__ idx_i, float* __restrict__ out_idx)
{
    __shared__ float xs[8][IND];   // 24 KB
    __shared__ float hs[8][HID];   // 16 KB
    __shared__ float zs[8][CBD];   //  8 KB
    __shared__ float bd_s[4][8];
    __shared__ int   bi_s[4][8];
    __shared__ int   tok_s[8];

    int n = cnt[0]; if (n > NTOK) n = NTOK; if (n < 0) n = 0;
    const int t = threadIdx.x;
    const int nb = (n + 7) >> 3;

    for (int ib = blockIdx.x; ib < nb; ib += gridDim.x) {
        const int base = ib * 8;
        if (t < 8) {
            int fi = base + t; if (fi > n - 1) fi = n - 1;
            tok_s[t] = flags[fi];
        }
        __syncthreads();

        // stage 8 x-rows: 1536 float4, 6 per thread
        #pragma unroll
        for (int s = 0; s < 6; ++s) {
            int slot = t + s * 256;
            int tt = slot / 192, c4 = slot - tt * 192;
            *(float4*)&xs[tt][c4 * 4] =
                *(const float4*)(x + (size_t)tok_s[tt] * IND + c4 * 4);
        }
        __syncthreads();

        // h = relu(x @ W1 + b1): thread t owns cols j=t and j=t+256 for all 8 toks
        {
            float a0[8], a1[8];
            float bb0 = b1[t], bb1 = b1[t + 256];
            #pragma unroll
            for (int tt = 0; tt < 8; ++tt) { a0[tt] = bb0; a1[tt] = bb1; }
            #pragma unroll 4
            for (int k = 0; k < IND; ++k) {
                float w0 = W1[(size_t)k * HID + t];
                float w1 = W1[(size_t)k * HID + t + 256];
                #pragma unroll
                for (int tt = 0; tt < 8; ++tt) {
                    float xv = xs[tt][k];
                    a0[tt] = fmaf(xv, w0, a0[tt]);
                    a1[tt] = fmaf(xv, w1, a1[tt]);
                }
            }
            #pragma unroll
            for (int tt = 0; tt < 8; ++tt) {
                hs[tt][t]       = fmaxf(a0[tt], 0.f);
                hs[tt][t + 256] = fmaxf(a1[tt], 0.f);
            }
        }
        __syncthreads();

        // z = h @ W2 + b2: thread t owns col c=t for all 8 toks
        {
            float az[8];
            float bz = b2[t];
            #pragma unroll
            for (int tt = 0; tt < 8; ++tt) az[tt] = bz;
            #pragma unroll 4
            for (int k = 0; k < HID; ++k) {
                float w = W2[(size_t)k * CBD + t];
                #pragma unroll
                for (int tt = 0; tt < 8; ++tt)
                    az[tt] = fmaf(hs[tt][k], w, az[tt]);
            }
            #pragma unroll
            for (int tt = 0; tt < 8; ++tt) zs[tt][t] = az[tt];
        }
        __syncthreads();

        // dists + argmin: wave wv owns codes [wv*128, wv*128+128)
        {
            const int wv = t >> 6, l = t & 63;
            float4 zv[8];
            #pragma unroll
            for (int tt = 0; tt < 8; ++tt) zv[tt] = *(const float4*)&zs[tt][l * 4];
            float bd[8]; int bi[8];
            #pragma unroll
            for (int tt = 0; tt < 8; ++tt) { bd[tt] = 3.4e38f; bi[tt] = 0x7fffffff; }
            for (int cc = 0; cc < 128; ++cc) {
                int c = wv * 128 + cc;
                float4 cv = *(const float4*)(cb + (size_t)c * CBD + l * 4);
                float cs = csq[c];
                #pragma unroll
                for (int tt = 0; tt < 8; ++tt) {
                    float p = zv[tt].x * cv.x + zv[tt].y * cv.y + zv[tt].z * cv.z + zv[tt].w * cv.w;
                    #pragma unroll
                    for (int mm = 32; mm; mm >>= 1) p += __shfl_xor(p, mm, 64);
                    float d = cs - 2.f * p;
                    if (d < bd[tt]) { bd[tt] = d; bi[tt] = c; }  // ascending c -> keeps first
                }
            }
            if (l == 0) {
                #pragma unroll
                for (int tt = 0; tt < 8; ++tt) { bd_s[wv][tt] = bd[tt]; bi_s[wv][tt] = bi[tt]; }
            }
        }
        __syncthreads();

        if (t < 8) {
            const int tt = t;
            float d = bd_s[0][tt]; int i = bi_s[0][tt];
            #pragma unroll
            for (int wv = 1; wv < 4; ++wv) {
                float od = bd_s[wv][tt]; int oi = bi_s[wv][tt];
                if (od < d || (od == d && oi < i)) { d = od; i = oi; }
            }
            if (base + tt < n) {
                int tok = tok_s[tt];
                idx_i[tok] = i; out_idx[tok] = (float)i;
            }
        }
        __syncthreads();
    }
}

// ---------------------------------------------------------------------------
// ReconTable = decoder(codebook): one block per code
// ---------------------------------------------------------------------------
__global__ __launch_bounds__(256) void table_pre(
    const float* __restrict__ cb, const float* __restrict__ W3,
    const float* __restrict__ b3, const float* __restrict__ W4,
    const float* __restrict__ b4, float* __restrict__ table)
{
    __shared__ float crow[CBD];
    __shared__ float h2[HID];
    const int c = blockIdx.x;
    const int t = threadIdx.x;
    crow[t] = cb[(size_t)c * CBD + t];
    __syncthreads();
    #pragma unroll
    for (int s = 0; s < 2; ++s) {
        int j = t + s * 256;
        float acc = b3[j];
        for (int k = 0; k < CBD; ++k) acc = fmaf(crow[k], W3[(size_t)k * HID + j], acc);
        h2[j] = fmaxf(acc, 0.f);
    }
    __syncthreads();
    #pragma unroll
    for (int s = 0; s < 3; ++s) {
        int j = t + s * 256;
        float acc = b4[j];
        for (int k = 0; k < HID; ++k) acc = fmaf(h2[k], W4[(size_t)k * IND + j], acc);
        table[(size_t)c * IND + j] = acc;
    }
}

// ---------------------------------------------------------------------------
// recon gather
// ---------------------------------------------------------------------------
__global__ __launch_bounds__(256) void gather_kernel(
    const int* __restrict__ idx, const float* __restrict__ table,
    float* __restrict__ out)
{
    unsigned i = blockIdx.x * 256u + threadIdx.x;   // float4 index, total NTOK*192
    unsigned tok = i / 192u;
    unsigned c = i - tok * 192u;
    int id = idx[tok];
    ((float4*)out)[i] = ((const float4*)table)[(size_t)id * 192 + c];
}

__global__ void finalize_kernel(const float* __restrict__ accum,
                                float* __restrict__ out_loss)
{
    out_loss[0] = accum[0] * (1.0f / 16777216.0f);   // mean over NTOK*CBD
}

// ---------------------------------------------------------------------------
extern "C" void kernel_launch(void* const* d_in, const int* in_sizes, int n_in,
                              void* d_out, int out_size, void* d_ws, size_t ws_size,
                              hipStream_t stream) {
    const float* x  = (const float*)d_in[0];
    const float* W1 = (const float*)d_in[1];
    const float* b1 = (const float*)d_in[2];
    const float* W2 = (const float*)d_in[3];
    const float* b2 = (const float*)d_in[4];
    const float* cb = (const float*)d_in[5];
    const float* W3 = (const float*)d_in[6];
    const float* b3 = (const float*)d_in[7];
    const float* W4 = (const float*)d_in[8];
    const float* b4 = (const float*)d_in[9];

    char* ws = (char*)d_ws;
    u32*  Hpk   = (u32*)(ws + OFF_H);
    u32*  Zpk   = (u32*)(ws + OFF_Z);
    u16*  W1h   = (u16*)(ws + OFF_W1H);
    u16*  W1l   = (u16*)(ws + OFF_W1L);
    u16*  W2h   = (u16*)(ws + OFF_W2H);
    u16*  W2l   = (u16*)(ws + OFF_W2L);
    u16*  CBh   = (u16*)(ws + OFF_CBH);
    u16*  CBl   = (u16*)(ws + OFF_CBL);
    float* csq  = (float*)(ws + OFF_CSQ);
    float* part = (float*)(ws + OFF_PART);
    float* table = (float*)(ws + OFF_TABLE);
    float* zsq  = (float*)(ws + OFF_ZSQ);
    int*   idx_i = (int*)(ws + OFF_IDX);
    int*   flags = (int*)(ws + OFF_FLAGS);
    int*   cnt   = (int*)(ws + OFF_CNT);
    float* accum = (float*)(ws + OFF_CNT + 4);

    float* out      = (float*)d_out;
    float* out_idx  = out + OUT_IDX_OFF;
    float* out_loss = out + OUT_LOSS_OFF;

    cbsplit<<<CBS, 256, 0, stream>>>(cb, CBh, CBl, csq);
    wsplit<<<HID, 256, 0, stream>>>(W1, W1h, W1l, IND, HID);   // W1T [512][768]
    wsplit<<<CBD, 256, 0, stream>>>(W2, W2h, W2l, HID, CBD);   // W2T [256][512]

    // h = relu(x @ W1 + b1) -> packed planes
    gemm3<0, 0><<<dim3(HID / 128, NTOK / 128), 256, 0, stream>>>(
        x, (const u32*)nullptr, W1h, W1l, b1, Hpk, (float*)nullptr, NTOK, HID, IND);
    // z = h @ W2 + b2 -> packed planes
    gemm3<1, 1><<<dim3(CBD / 128, NTOK / 128), 256, 0, stream>>>(
        (const float*)nullptr, Hpk, W2h, W2l, b2, Zpk, (float*)nullptr, NTOK, CBD, HID);

    // H region is dead from here on; zero cnt/accum AFTER GEMM1's Hpk writes
    // (round-2 bug: zeroing first got clobbered -> garbage cnt -> OOB flags write)
    hipMemsetAsync(cnt, 0, 8, stream);

    zsq_pk<<<NTOK / 4, 256, 0, stream>>>(Zpk, zsq);

    // dists top-2 partials: dist = c_sq - 2 * (z . c)
    gemm3<1, 2><<<dim3(CBS / 128, NTOK / 128), 256, 0, stream>>>(
        (const float*)nullptr, Zpk, CBh, CBl, csq, (u32*)nullptr, part, NTOK, CBS, CBD);

    table_pre<<<CBS, 256, 0, stream>>>(cb, W3, b3, W4, b4, table);

    vq_reduce<<<NTOK / 256, 256, 0, stream>>>(part, zsq, out_idx, idx_i, cnt, accum, flags);

    // batched fixup: 8 tokens/block-iter, grid-stride. 48KB LDS -> 3 blocks/CU.
    fixup<<<1024, 256, 0, stream>>>(cnt, flags, x, W1, b1, W2, b2, cb, csq, idx_i, out_idx);

    gather_kernel<<<(NTOK * (IND / 4)) / 256, 256, 0, stream>>>(idx_i, table, out);

    finalize_kernel<<<1, 1, 0, stream>>>(accum, out_loss);
}

// Round 2
// 947.323 us; speedup vs baseline: 1.0757x; 1.0396x over previous
//
#include <hip/hip_runtime.h>

typedef unsigned short u16;
typedef unsigned int   u32;
typedef __attribute__((ext_vector_type(8))) short short8;
typedef __attribute__((ext_vector_type(4))) float f32x4;

#define NTOK 65536
#define IND  768
#define HID  512
#define CBD  256
#define CBS  512

// d_out layout (floats): recon[NTOK*IND], indices-as-float[NTOK], loss[1]
#define OUT_IDX_OFF   ((size_t)NTOK * IND)
#define OUT_LOSS_OFF  (OUT_IDX_OFF + NTOK)

// ws byte offsets (total 203,950,080 <= proven round-1 usage 203,950,084)
#define OFF_H      ((size_t)0)            // Hpack u32 [NTOK][HID]  = 134,217,728 B
#define OFF_Z      ((size_t)134217728)    // Zpack u32 [NTOK][CBD]  =  67,108,864 B
#define OFF_W1H    ((size_t)201326592)    // W1T hi u16 [HID][IND]
#define OFF_W1L    ((size_t)202113024)
#define OFF_W2H    ((size_t)202899456)    // W2T hi u16 [CBD][HID]
#define OFF_W2L    ((size_t)203161600)
#define OFF_CBH    ((size_t)203423744)    // CB  hi u16 [CBS][CBD]
#define OFF_CBL    ((size_t)203685888)
#define OFF_CSQ    ((size_t)203948032)    // c_sq f32 [CBS]
// aliases inside H region (H dead after GEMM2 consumes it; all writers below
// run after GEMM2 in stream order)
#define OFF_PART   ((size_t)0)            // partials float4 [NTOK][8]  = 8,388,608 B
#define OFF_TABLE  ((size_t)8388608)      // ReconTable f32 [CBS][IND]  = 1,572,864 B
#define OFF_ZSQ    ((size_t)9961472)      // zsq f32 [NTOK]             =   262,144 B
#define OFF_IDX    ((size_t)10223616)     // idx int [NTOK]
#define OFF_FLAGS  ((size_t)10485760)     // flag list int [NTOK]
#define OFF_CNT    ((size_t)10747904)     // [0]=flag_count int, [4]=accum float

__device__ __forceinline__ u16 f2bf(float f) {
    u32 u = __float_as_uint(f);
    return (u16)((u + 0x7fffu + ((u >> 16) & 1u)) >> 16);
}
__device__ __forceinline__ float bf2f(u16 h) {
    return __uint_as_float(((u32)h) << 16);
}

// ---------------------------------------------------------------------------
// codebook split + c_sq : one block per code
// ---------------------------------------------------------------------------
__global__ __launch_bounds__(256) void cbsplit(
    const float* __restrict__ cb, u16* __restrict__ hi, u16* __restrict__ lo,
    float* __restrict__ csq)
{
    int c = blockIdx.x, t = threadIdx.x;
    float v = cb[(size_t)c * CBD + t];
    u16 h = f2bf(v); u16 l = f2bf(v - bf2f(h));
    hi[(size_t)c * CBD + t] = h; lo[(size_t)c * CBD + t] = l;
    __shared__ float red[256];
    red[t] = v * v; __syncthreads();
    for (int s = 128; s; s >>= 1) { if (t < s) red[t] += red[t + s]; __syncthreads(); }
    if (!t) csq[c] = red[0];
}

// ---------------------------------------------------------------------------
// weight transpose+split: W [K,N] fp32 -> WT hi/lo bf16 [N,K]. block per n.
// ---------------------------------------------------------------------------
__global__ __launch_bounds__(256) void wsplit(
    const float* __restrict__ W, u16* __restrict__ hi, u16* __restrict__ lo,
    int K, int N)
{
    int n = blockIdx.x;
    for (int k = threadIdx.x; k < K; k += 256) {
        float v = W[(size_t)k * N + n];
        u16 h = f2bf(v); u16 l = f2bf(v - bf2f(h));
        hi[(size_t)n * K + k] = h; lo[(size_t)n * K + k] = l;
    }
}

// ---------------------------------------------------------------------------
// bf16x3 MFMA GEMM: 128x128 tile, BK=32, 256 thr (4 waves), 4x4 16x16x32 frags
// AMODE 0: A fp32 [M,K] (convert in staging)   AMODE 1: A packed hi|lo u32 [M,K]
// EPI 0: relu(acc+bias) -> packed u32          EPI 1: acc+bias -> packed u32
// EPI 2: dist = bias[n] - 2*acc; per-row/wave-col top2 -> partials[row][bx*2+wcol]
// ---------------------------------------------------------------------------
template<int AMODE, int EPI>
__global__ __launch_bounds__(256, 2) void gemm3(
    const float* __restrict__ Af, const u32* __restrict__ Apk,
    const u16* __restrict__ Bhi, const u16* __restrict__ Blo,
    const float* __restrict__ bias,
    u32* __restrict__ Opk, float* __restrict__ Opart,
    int M, int N, int K)
{
    __shared__ u16 lds[4 * 128 * 40];         // 40 KB: Ahi, Alo, Bhi, Blo [128][40]
    u16* sAh = lds;
    u16* sAl = lds + 5120;
    u16* sBh = lds + 10240;
    u16* sBl = lds + 15360;
    const int tid  = threadIdx.x;
    const int m0 = blockIdx.y * 128, n0 = blockIdx.x * 128;
    const int w = tid >> 6, lane = tid & 63, quad = lane >> 4, l15 = lane & 15;
    const int wm = (w & 1) * 64, wn = (w >> 1) * 64;

    f32x4 acc[4][4] = {};

    for (int k0 = 0; k0 < K; k0 += 32) {
        __syncthreads();
        if (AMODE == 0) {
            #pragma unroll
            for (int s = 0; s < 4; ++s) {
                int slot = tid + s * 256;
                int m = slot >> 3, kg = (slot & 7) << 2;
                float4 v = *(const float4*)(Af + (size_t)(m0 + m) * K + k0 + kg);
                u16 h0 = f2bf(v.x), h1 = f2bf(v.y), h2 = f2bf(v.z), h3 = f2bf(v.w);
                ushort4 hv = {h0, h1, h2, h3};
                ushort4 lv = {f2bf(v.x - bf2f(h0)), f2bf(v.y - bf2f(h1)),
                              f2bf(v.z - bf2f(h2)), f2bf(v.w - bf2f(h3))};
                *(ushort4*)&sAh[m * 40 + kg] = hv;
                *(ushort4*)&sAl[m * 40 + kg] = lv;
            }
        } else {
            #pragma unroll
            for (int s = 0; s < 4; ++s) {
                int slot = tid + s * 256;
                int m = slot >> 3, ke = (slot & 7) << 2;   // 4 elems per uint4
                uint4 u = *(const uint4*)(Apk + (size_t)(m0 + m) * K + k0 + ke);
                ushort4 hv = {(u16)(u.x & 0xffff), (u16)(u.y & 0xffff),
                              (u16)(u.z & 0xffff), (u16)(u.w & 0xffff)};
                ushort4 lv = {(u16)(u.x >> 16), (u16)(u.y >> 16),
                              (u16)(u.z >> 16), (u16)(u.w >> 16)};
                *(ushort4*)&sAh[m * 40 + ke] = hv;
                *(ushort4*)&sAl[m * 40 + ke] = lv;
            }
        }
        // B planes [N,K] bf16 -> LDS
        #pragma unroll
        for (int s = 0; s < 4; ++s) {
            int slot = tid + s * 256;                 // 1024 slots, 512 per plane
            int n = (slot & 511) >> 2, ku = slot & 3; // 8 elems per uint4
            const u16* src = (slot < 512) ? Bhi : Blo;
            u16* dst = (slot < 512) ? sBh : sBl;
            uint4 u = *(const uint4*)(src + (size_t)(n0 + n) * K + k0 + ku * 8);
            *(uint4*)&dst[n * 40 + ku * 8] = u;
        }
        __syncthreads();

        short8 ah[4], al[4], bh[4], bl[4];
        const int ko = quad * 8;
        #pragma unroll
        for (int i = 0; i < 4; ++i) {
            int ar = wm + i * 16 + l15;
            int br = wn + i * 16 + l15;
            ah[i] = *(const short8*)&sAh[ar * 40 + ko];
            al[i] = *(const short8*)&sAl[ar * 40 + ko];
            bh[i] = *(const short8*)&sBh[br * 40 + ko];
            bl[i] = *(const short8*)&sBl[br * 40 + ko];
        }
        #pragma unroll
        for (int i = 0; i < 4; ++i)
            #pragma unroll
            for (int j = 0; j < 4; ++j) {
                acc[i][j] = __builtin_amdgcn_mfma_f32_16x16x32_bf16(ah[i], bh[j], acc[i][j], 0, 0, 0);
                acc[i][j] = __builtin_amdgcn_mfma_f32_16x16x32_bf16(ah[i], bl[j], acc[i][j], 0, 0, 0);
                acc[i][j] = __builtin_amdgcn_mfma_f32_16x16x32_bf16(al[i], bh[j], acc[i][j], 0, 0, 0);
            }
    }

    // epilogue. C/D layout: col = n-tile + l15, row = m-tile + quad*4 + r
    if (EPI <= 1) {
        float bn[4];
        #pragma unroll
        for (int j = 0; j < 4; ++j) bn[j] = bias[n0 + wn + j * 16 + l15];
        #pragma unroll
        for (int i = 0; i < 4; ++i)
            #pragma unroll
            for (int r = 0; r < 4; ++r) {
                int row = m0 + wm + i * 16 + quad * 4 + r;
                #pragma unroll
                for (int j = 0; j < 4; ++j) {
                    float v = acc[i][j][r] + bn[j];
                    if (EPI == 0) v = fmaxf(v, 0.f);
                    u16 h = f2bf(v); u16 l = f2bf(v - bf2f(h));
                    Opk[(size_t)row * N + n0 + wn + j * 16 + l15] = (u32)h | ((u32)l << 16);
                }
            }
    } else {
        float cs[4]; int cidx[4];
        #pragma unroll
        for (int j = 0; j < 4; ++j) {
            cidx[j] = n0 + wn + j * 16 + l15;
            cs[j] = bias[cidx[j]];
        }
        const int nparts = gridDim.x * 2;
        const int pslot  = blockIdx.x * 2 + (w >> 1);   // distinct per wave-column!
        #pragma unroll
        for (int i = 0; i < 4; ++i)
            #pragma unroll
            for (int r = 0; r < 4; ++r) {
                int row = m0 + wm + i * 16 + quad * 4 + r;
                float d1 = 3.4e38f, d2 = 3.4e38f; int i1 = 0x7fffffff;
                #pragma unroll
                for (int j = 0; j < 4; ++j) {
                    float v = fmaf(-2.0f, acc[i][j][r], cs[j]);
                    if (v < d1) { d2 = d1; d1 = v; i1 = cidx[j]; }
                    else d2 = fminf(d2, v);
                }
                #pragma unroll
                for (int mm = 1; mm < 16; mm <<= 1) {
                    float od1 = __shfl_xor(d1, mm, 64);
                    float od2 = __shfl_xor(d2, mm, 64);
                    int   oi1 = __shfl_xor(i1, mm, 64);
                    if (od1 < d1 || (od1 == d1 && oi1 < i1)) { d2 = fminf(d1, od2); d1 = od1; i1 = oi1; }
                    else d2 = fminf(d2, od1);
                }
                if (l15 == 0) {
                    float4 o = {d1, d2, __int_as_float(i1), 0.f};
                    *(float4*)&Opart[((size_t)row * nparts + pslot) * 4] = o;
                }
            }
    }
}

// ---------------------------------------------------------------------------
// zsq from packed z
// ---------------------------------------------------------------------------
__global__ __launch_bounds__(256) void zsq_pk(
    const u32* __restrict__ Zpk, float* __restrict__ zsq)
{
    int tok = blockIdx.x * 4 + (threadIdx.x >> 6);
    int lane = threadIdx.x & 63;
    uint4 u = *(const uint4*)(Zpk + (size_t)tok * CBD + lane * 4);
    float z0 = bf2f((u16)(u.x & 0xffff)) + bf2f((u16)(u.x >> 16));
    float z1 = bf2f((u16)(u.y & 0xffff)) + bf2f((u16)(u.y >> 16));
    float z2 = bf2f((u16)(u.z & 0xffff)) + bf2f((u16)(u.z >> 16));
    float z3 = bf2f((u16)(u.w & 0xffff)) + bf2f((u16)(u.w >> 16));
    float s = z0 * z0 + z1 * z1 + z2 * z2 + z3 * z3;
    #pragma unroll
    for (int off = 32; off; off >>= 1) s += __shfl_down(s, off, 64);
    if (!lane) zsq[tok] = s;
}

// ---------------------------------------------------------------------------
// combine per-slot top2 partials (8 per token) -> idx, flags, commit sum
// threshold 0.01: bf16x3 dist error RMS ~2e-4, extreme tail ~2e-3 -> >=5x
// margin; near-ties (<1e-5) remain flagged under both 0.05 and 0.01 and are
// resolved by the byte-identical exact path.
// ---------------------------------------------------------------------------
__global__ __launch_bounds__(256) void vq_reduce(
    const float* __restrict__ part, const float* __restrict__ zsq,
    float* __restrict__ out_idx, int* __restrict__ idx_i,
    int* __restrict__ cnt, float* __restrict__ accum, int* __restrict__ flags)
{
    int tok = blockIdx.x * 256 + threadIdx.x;
    float d1 = 3.4e38f, d2 = 3.4e38f; int i1 = 0x7fffffff;
    #pragma unroll
    for (int nb = 0; nb < 8; ++nb) {
        float4 p = *(const float4*)&part[((size_t)tok * 8 + nb) * 4];
        float pd1 = p.x, pd2 = p.y; int pi1 = __float_as_int(p.z);
        if (pd1 < d1 || (pd1 == d1 && pi1 < i1)) { d2 = fminf(d1, pd2); d1 = pd1; i1 = pi1; }
        else d2 = fminf(d2, pd1);
    }
    out_idx[tok] = (float)i1;
    idx_i[tok] = i1;
    if (d2 - d1 < 0.01f) {
        int p = atomicAdd(cnt, 1);
        if (p >= 0 && p < NTOK) flags[p] = tok;
    }
    float c = zsq[tok] + d1;      // ||z||^2 + c_sq - 2 dot = ||z - q||^2
    __shared__ float red[256];
    red[threadIdx.x] = c; __syncthreads();
    for (int s = 128; s; s >>= 1) { if (threadIdx.x < s) red[threadIdx.x] += red[threadIdx.x + s]; __syncthreads(); }
    if (!threadIdx.x) atomicAdd(accum, red[0]);
}

// ---------------------------------------------------------------------------
// exact fp32 recompute of argmin for near-tie tokens.
// Round-2 rewrite: the 8-token batch was LDS-pipe issue-bound (16K ds ops/wave:
// per-k b32 broadcasts in GEMM1/2 + dist shuffles -> 252us). GEMM1/2 now use
// register tiling: thread owns (token-group x 4 cols), per 4-k step reads
// wave-uniform ds_read_b128 broadcasts + coalesced float4 W loads. Per-(tok,col)
// FMA chains stay ascending-k with identical operands -> hs/zs bitwise
// identical to round-1. dist/argmin phases copied verbatim (same butterfly
// order, same tie-breaks).
// ---------------------------------------------------------------------------
__global__ __launch_bounds__(256) void fixup(
    const int* __restrict__ cnt, const int* __restrict__ flags,
    const float* __restrict__ x, const float* __restrict__ W1, const float* __restrict__ b1,
    const float* __restrict__ W2, const float* __restrict__ b2,
    const float* __restrict__ cb, const float* __restrict__ csq,
    int* __restrict__ idx_i, float* __restrict__ out_idx)
{
    __shared__ float xs[8][IND];   // 24 KB
    __shared__ float hs[8][HID];   // 16 KB
    __shared__ float zs[8][CBD];   //  8 KB
    __shared__ float bd_s[4][8];
    __shared__ int   bi_s[4][8];
    __shared__ int   tok_s[8];

    int n = cnt[0]; if (n > NTOK) n = NTOK; if (n < 0) n = 0;
    const int t = threadIdx.x;
    const int nb = (n + 7) >> 3;

    for (int ib = blockIdx.x; ib < nb; ib += gridDim.x) {
        const int base = ib * 8;
        if (t < 8) {
            int fi = base + t; if (fi > n - 1) fi = n - 1;
            tok_s[t] = flags[fi];
        }
        __syncthreads();

        // stage 8 x-rows: 1536 float4, 6 per thread
        #pragma unroll
        for (int s = 0; s < 6; ++s) {
            int slot = t + s * 256;
            int tt = slot / 192, c4 = slot - tt * 192;
            *(float4*)&xs[tt][c4 * 4] =
                *(const float4*)(x + (size_t)tok_s[tt] * IND + c4 * 4);
        }
        __syncthreads();

        // h = relu(x @ W1 + b1): thread owns 4 tokens (tg) x 4 cols (j0..j0+3)
        {
            const int tg = t >> 7;          // 0..1 -> tokens tg*4..tg*4+3
            const int j0 = (t & 127) * 4;   // 4 consecutive cols
            float a[4][4];
            float4 bb = *(const float4*)(b1 + j0);
            #pragma unroll
            for (int ti = 0; ti < 4; ++ti) {
                a[ti][0] = bb.x; a[ti][1] = bb.y; a[ti][2] = bb.z; a[ti][3] = bb.w;
            }
            for (int k4 = 0; k4 < IND / 4; ++k4) {
                float4 xv[4];
                #pragma unroll
                for (int ti = 0; ti < 4; ++ti)
                    xv[ti] = *(const float4*)&xs[tg * 4 + ti][k4 * 4];
                #pragma unroll
                for (int kk = 0; kk < 4; ++kk) {
                    float4 wv = *(const float4*)(W1 + (size_t)(k4 * 4 + kk) * HID + j0);
                    #pragma unroll
                    for (int ti = 0; ti < 4; ++ti) {
                        float xk = (kk == 0) ? xv[ti].x : (kk == 1) ? xv[ti].y
                                 : (kk == 2) ? xv[ti].z : xv[ti].w;
                        a[ti][0] = fmaf(xk, wv.x, a[ti][0]);
                        a[ti][1] = fmaf(xk, wv.y, a[ti][1]);
                        a[ti][2] = fmaf(xk, wv.z, a[ti][2]);
                        a[ti][3] = fmaf(xk, wv.w, a[ti][3]);
                    }
                }
            }
            #pragma unroll
            for (int ti = 0; ti < 4; ++ti) {
                float4 o = {fmaxf(a[ti][0], 0.f), fmaxf(a[ti][1], 0.f),
                            fmaxf(a[ti][2], 0.f), fmaxf(a[ti][3], 0.f)};
                *(float4*)&hs[tg * 4 + ti][j0] = o;
            }
        }
        __syncthreads();

        // z = h @ W2 + b2: thread owns 2 tokens (tg) x 4 cols (c0..c0+3)
        {
            const int tg = t >> 6;          // 0..3 -> tokens tg*2, tg*2+1
            const int c0 = (t & 63) * 4;
            float az[2][4];
            float4 bz = *(const float4*)(b2 + c0);
            #pragma unroll
            for (int ti = 0; ti < 2; ++ti) {
                az[ti][0] = bz.x; az[ti][1] = bz.y; az[ti][2] = bz.z; az[ti][3] = bz.w;
            }
            for (int k4 = 0; k4 < HID / 4; ++k4) {
                float4 hv[2];
                #pragma unroll
                for (int ti = 0; ti < 2; ++ti)
                    hv[ti] = *(const float4*)&hs[tg * 2 + ti][k4 * 4];
                #pragma unroll
                for (int kk = 0; kk < 4; ++kk) {
                    float4 wv = *(const float4*)(W2 + (size_t)(k4 * 4 + kk) * CBD + c0);
                    #pragma unroll
                    for (int ti = 0; ti < 2; ++ti) {
                        float hk = (kk == 0) ? hv[ti].x : (kk == 1) ? hv[ti].y
                                 : (kk == 2) ? hv[ti].z : hv[ti].w;
                        az[ti][0] = fmaf(hk, wv.x, az[ti][0]);
                        az[ti][1] = fmaf(hk, wv.y, az[ti][1]);
                        az[ti][2] = fmaf(hk, wv.z, az[ti][2]);
                        az[ti][3] = fmaf(hk, wv.w, az[ti][3]);
                    }
                }
            }
            #pragma unroll
            for (int ti = 0; ti < 2; ++ti) {
                float4 o = {az[ti][0], az[ti][1], az[ti][2], az[ti][3]};
                *(float4*)&zs[tg * 2 + ti][c0] = o;
            }
        }
        __syncthreads();

        // dists + argmin: wave wv owns codes [wv*128, wv*128+128)  (verbatim)
        {
            const int wv = t >> 6, l = t & 63;
            float4 zv[8];
            #pragma unroll
            for (int tt = 0; tt < 8; ++tt) zv[tt] = *(const float4*)&zs[tt][l * 4];
            float bd[8]; int bi[8];
            #pragma unroll
            for (int tt = 0; tt < 8; ++tt) { bd[tt] = 3.4e38f; bi[tt] = 0x7fffffff; }
            for (int cc = 0; cc < 128; ++cc) {
                int c = wv * 128 + cc;
                float4 cv = *(const float4*)(cb + (size_t)c * CBD + l * 4);
                float cs = csq[c];
                #pragma unroll
                for (int tt = 0; tt < 8; ++tt) {
                    float p = zv[tt].x * cv.x + zv[tt].y * cv.y + zv[tt].z * cv.z + zv[tt].w * cv.w;
                    #pragma unroll
                    for (int mm = 32; mm; mm >>= 1) p += __shfl_xor(p, mm, 64);
                    float d = cs - 2.f * p;
                    if (d < bd[tt]) { bd[tt] = d; bi[tt] = c; }  // ascending c -> keeps first
                }
            }
            if (l == 0) {
                #pragma unroll
                for (int tt = 0; tt < 8; ++tt) { bd_s[wv][tt] = bd[tt]; bi_s[wv][tt] = bi[tt]; }
            }
        }
        __syncthreads();

        if (t < 8) {
            const int tt = t;
            float d = bd_s[0][tt]; int i = bi_s[0][tt];
            #pragma unroll
            for (int wv = 1; wv < 4; ++wv) {
                float od = bd_s[wv][tt]; int oi = bi_s[wv][tt];
                if (od < d || (od == d && oi < i)) { d = od; i = oi; }
            }
            if (base + tt < n) {
                int tok = tok_s[tt];
                idx_i[tok] = i; out_idx[tok] = (float)i;
            }
        }
        __syncthreads();
    }
}

// ---------------------------------------------------------------------------
// ReconTable = decoder(codebook): one block per code
// ---------------------------------------------------------------------------
__global__ __launch_bounds__(256) void table_pre(
    const float* __restrict__ cb, const float* __restrict__ W3,
    const float* __restrict__ b3, const float* __restrict__ W4,
    const float* __restrict__ b4, float* __restrict__ table)
{
    __shared__ float crow[CBD];
    __shared__ float h2[HID];
    const int c = blockIdx.x;
    const int t = threadIdx.x;
    crow[t] = cb[(size_t)c * CBD + t];
    __syncthreads();
    #pragma unroll
    for (int s = 0; s < 2; ++s) {
        int j = t + s * 256;
        float acc = b3[j];
        for (int k = 0; k < CBD; ++k) acc = fmaf(crow[k], W3[(size_t)k * HID + j], acc);
        h2[j] = fmaxf(acc, 0.f);
    }
    __syncthreads();
    #pragma unroll
    for (int s = 0; s < 3; ++s) {
        int j = t + s * 256;
        float acc = b4[j];
        for (int k = 0; k < HID; ++k) acc = fmaf(h2[k], W4[(size_t)k * IND + j], acc);
        table[(size_t)c * IND + j] = acc;
    }
}

// ---------------------------------------------------------------------------
// recon gather
// ---------------------------------------------------------------------------
__global__ __launch_bounds__(256) void gather_kernel(
    const int* __restrict__ idx, const float* __restrict__ table,
    float* __restrict__ out)
{
    unsigned i = blockIdx.x * 256u + threadIdx.x;   // float4 index, total NTOK*192
    unsigned tok = i / 192u;
    unsigned c = i - tok * 192u;
    int id = idx[tok];
    ((float4*)out)[i] = ((const float4*)table)[(size_t)id * 192 + c];
}

__global__ void finalize_kernel(const float* __restrict__ accum,
                                float* __restrict__ out_loss)
{
    out_loss[0] = accum[0] * (1.0f / 16777216.0f);   // mean over NTOK*CBD
}

// ---------------------------------------------------------------------------
extern "C" void kernel_launch(void* const* d_in, const int* in_sizes, int n_in,
                              void* d_out, int out_size, void* d_ws, size_t ws_size,
                              hipStream_t stream) {
    const float* x  = (const float*)d_in[0];
    const float* W1 = (const float*)d_in[1];
    const float* b1 = (const float*)d_in[2];
    const float* W2 = (const float*)d_in[3];
    const float* b2 = (const float*)d_in[4];
    const float* cb = (const float*)d_in[5];
    const float* W3 = (const float*)d_in[6];
    const float* b3 = (const float*)d_in[7];
    const float* W4 = (const float*)d_in[8];
    const float* b4 = (const float*)d_in[9];

    char* ws = (char*)d_ws;
    u32*  Hpk   = (u32*)(ws + OFF_H);
    u32*  Zpk   = (u32*)(ws + OFF_Z);
    u16*  W1h   = (u16*)(ws + OFF_W1H);
    u16*  W1l   = (u16*)(ws + OFF_W1L);
    u16*  W2h   = (u16*)(ws + OFF_W2H);
    u16*  W2l   = (u16*)(ws + OFF_W2L);
    u16*  CBh   = (u16*)(ws + OFF_CBH);
    u16*  CBl   = (u16*)(ws + OFF_CBL);
    float* csq  = (float*)(ws + OFF_CSQ);
    float* part = (float*)(ws + OFF_PART);
    float* table = (float*)(ws + OFF_TABLE);
    float* zsq  = (float*)(ws + OFF_ZSQ);
    int*   idx_i = (int*)(ws + OFF_IDX);
    int*   flags = (int*)(ws + OFF_FLAGS);
    int*   cnt   = (int*)(ws + OFF_CNT);
    float* accum = (float*)(ws + OFF_CNT + 4);

    float* out      = (float*)d_out;
    float* out_idx  = out + OUT_IDX_OFF;
    float* out_loss = out + OUT_LOSS_OFF;

    cbsplit<<<CBS, 256, 0, stream>>>(cb, CBh, CBl, csq);
    wsplit<<<HID, 256, 0, stream>>>(W1, W1h, W1l, IND, HID);   // W1T [512][768]
    wsplit<<<CBD, 256, 0, stream>>>(W2, W2h, W2l, HID, CBD);   // W2T [256][512]

    // h = relu(x @ W1 + b1) -> packed planes
    gemm3<0, 0><<<dim3(HID / 128, NTOK / 128), 256, 0, stream>>>(
        x, (const u32*)nullptr, W1h, W1l, b1, Hpk, (float*)nullptr, NTOK, HID, IND);
    // z = h @ W2 + b2 -> packed planes
    gemm3<1, 1><<<dim3(CBD / 128, NTOK / 128), 256, 0, stream>>>(
        (const float*)nullptr, Hpk, W2h, W2l, b2, Zpk, (float*)nullptr, NTOK, CBD, HID);

    // H region is dead from here on; zero cnt/accum AFTER GEMM1's Hpk writes
    // (round-2 bug: zeroing first got clobbered -> garbage cnt -> OOB flags write)
    hipMemsetAsync(cnt, 0, 8, stream);

    zsq_pk<<<NTOK / 4, 256, 0, stream>>>(Zpk, zsq);

    // dists top-2 partials: dist = c_sq - 2 * (z . c)
    gemm3<1, 2><<<dim3(CBS / 128, NTOK / 128), 256, 0, stream>>>(
        (const float*)nullptr, Zpk, CBh, CBl, csq, (u32*)nullptr, part, NTOK, CBS, CBD);

    table_pre<<<CBS, 256, 0, stream>>>(cb, W3, b3, W4, b4, table);

    vq_reduce<<<NTOK / 256, 256, 0, stream>>>(part, zsq, out_idx, idx_i, cnt, accum, flags);

    // batched fixup: 8 tokens/block-iter, grid-stride. 48KB LDS -> 3 blocks/CU.
    fixup<<<1024, 256, 0, stream>>>(cnt, flags, x, W1, b1, W2, b2, cb, csq, idx_i, out_idx);

    gather_kernel<<<(NTOK * (IND / 4)) / 256, 256, 0, stream>>>(idx_i, table, out);

    finalize_kernel<<<1, 1, 0, stream>>>(accum, out_loss);
}

// Round 3
// 917.982 us; speedup vs baseline: 1.1101x; 1.0320x over previous
//
#include <hip/hip_runtime.h>

typedef unsigned short u16;
typedef unsigned int   u32;
typedef __attribute__((ext_vector_type(8))) short short8;
typedef __attribute__((ext_vector_type(4))) float f32x4;

#define NTOK 65536
#define IND  768
#define HID  512
#define CBD  256
#define CBS  512

// d_out layout (floats): recon[NTOK*IND], indices-as-float[NTOK], loss[1]
#define OUT_IDX_OFF   ((size_t)NTOK * IND)
#define OUT_LOSS_OFF  (OUT_IDX_OFF + NTOK)

// ws byte offsets (total 203,950,080 <= proven round-1 usage 203,950,084)
#define OFF_H      ((size_t)0)            // Hpack u32 [NTOK][HID]  = 134,217,728 B
#define OFF_Z      ((size_t)134217728)    // Zpack u32 [NTOK][CBD]  =  67,108,864 B
#define OFF_W1H    ((size_t)201326592)    // W1T hi u16 [HID][IND]
#define OFF_W1L    ((size_t)202113024)
#define OFF_W2H    ((size_t)202899456)    // W2T hi u16 [CBD][HID]
#define OFF_W2L    ((size_t)203161600)
#define OFF_CBH    ((size_t)203423744)    // CB  hi u16 [CBS][CBD]
#define OFF_CBL    ((size_t)203685888)
#define OFF_CSQ    ((size_t)203948032)    // c_sq f32 [CBS]
// aliases inside H region (H dead after GEMM2 consumes it; all writers below
// run after GEMM2 in stream order)
#define OFF_PART   ((size_t)0)            // partials float4 [NTOK][8]  = 8,388,608 B
#define OFF_TABLE  ((size_t)8388608)      // ReconTable f32 [CBS][IND]  = 1,572,864 B
#define OFF_ZSQ    ((size_t)9961472)      // zsq f32 [NTOK]             =   262,144 B
#define OFF_IDX    ((size_t)10223616)     // idx int [NTOK]
#define OFF_FLAGS  ((size_t)10485760)     // flag list int [NTOK]
#define OFF_CNT    ((size_t)10747904)     // [0]=flag_count int, [4]=accum float

__device__ __forceinline__ u16 f2bf(float f) {
    u32 u = __float_as_uint(f);
    return (u16)((u + 0x7fffu + ((u >> 16) & 1u)) >> 16);
}
__device__ __forceinline__ float bf2f(u16 h) {
    return __uint_as_float(((u32)h) << 16);
}

// ---------------------------------------------------------------------------
// codebook split + c_sq : one block per code
// ---------------------------------------------------------------------------
__global__ __launch_bounds__(256) void cbsplit(
    const float* __restrict__ cb, u16* __restrict__ hi, u16* __restrict__ lo,
    float* __restrict__ csq)
{
    int c = blockIdx.x, t = threadIdx.x;
    float v = cb[(size_t)c * CBD + t];
    u16 h = f2bf(v); u16 l = f2bf(v - bf2f(h));
    hi[(size_t)c * CBD + t] = h; lo[(size_t)c * CBD + t] = l;
    __shared__ float red[256];
    red[t] = v * v; __syncthreads();
    for (int s = 128; s; s >>= 1) { if (t < s) red[t] += red[t + s]; __syncthreads(); }
    if (!t) csq[c] = red[0];
}

// ---------------------------------------------------------------------------
// weight transpose+split: W [K,N] fp32 -> WT hi/lo bf16 [N,K]. block per n.
// ---------------------------------------------------------------------------
__global__ __launch_bounds__(256) void wsplit(
    const float* __restrict__ W, u16* __restrict__ hi, u16* __restrict__ lo,
    int K, int N)
{
    int n = blockIdx.x;
    for (int k = threadIdx.x; k < K; k += 256) {
        float v = W[(size_t)k * N + n];
        u16 h = f2bf(v); u16 l = f2bf(v - bf2f(h));
        hi[(size_t)n * K + k] = h; lo[(size_t)n * K + k] = l;
    }
}

// ---------------------------------------------------------------------------
// bf16x3 MFMA GEMM: 128x128 tile, BK=32, 256 thr (4 waves), 4x4 16x16x32 frags
// AMODE 0: A fp32 [M,K] (convert in staging)   AMODE 1: A packed hi|lo u32 [M,K]
// EPI 0: relu(acc+bias) -> packed u32          EPI 1: acc+bias -> packed u32
// EPI 2: dist = bias[n] - 2*acc; per-row/wave-col top2 -> partials[row][bx*2+wcol]
//
// Round-3: (1) chunk-major LDS layout [chunk=k/8][row][8u16], stride 1040/chunk
// (+8 pad): ds_read_b128 fragment reads stripe banks 0,4..28 per 8-lane group
// (conflict-free); staging writes <=2-way. Was: row-stride-20-dword layout,
// gcd(20,32)=4 -> 2.5e7 conflict cycles/dispatch (~40us/CU). Same (row,k)
// data -> bitwise-identical MFMA inputs.
// (2) bijective XCD swizzle: the 4 n-blocks sharing an m-row's A tile were
// round-robined to 4 XCDs (A refetched ~2x from HBM); remap so consecutive
// logical blocks (same by) share an XCD L2.
// ---------------------------------------------------------------------------
#define CHS 1040   // u16 per chunk block: 128 rows * 8 + 8 pad
#define PLN (4 * CHS)

template<int AMODE, int EPI>
__global__ __launch_bounds__(256, 2) void gemm3(
    const float* __restrict__ Af, const u32* __restrict__ Apk,
    const u16* __restrict__ Bhi, const u16* __restrict__ Blo,
    const float* __restrict__ bias,
    u32* __restrict__ Opk, float* __restrict__ Opart,
    int M, int N, int K)
{
    __shared__ u16 lds[4 * PLN];              // 32.5 KB: Ahi, Alo, Bhi, Blo
    u16* sAh = lds;
    u16* sAl = lds + PLN;
    u16* sBh = lds + 2 * PLN;
    u16* sBl = lds + 3 * PLN;
    const int tid  = threadIdx.x;

    // XCD-aware bijective remap (all grids here have nwg % 8 == 0)
    const int nwg = gridDim.x * gridDim.y;
    const int hw  = blockIdx.y * gridDim.x + blockIdx.x;
    const int logical = (hw & 7) * (nwg >> 3) + (hw >> 3);
    const int bx = logical % gridDim.x;
    const int by = logical / gridDim.x;

    const int m0 = by * 128, n0 = bx * 128;
    const int w = tid >> 6, lane = tid & 63, quad = lane >> 4, l15 = lane & 15;
    const int wm = (w & 1) * 64, wn = (w >> 1) * 64;

    f32x4 acc[4][4] = {};

    for (int k0 = 0; k0 < K; k0 += 32) {
        __syncthreads();
        if (AMODE == 0) {
            #pragma unroll
            for (int s = 0; s < 4; ++s) {
                int slot = tid + s * 256;
                int m = slot >> 3, kg = (slot & 7) << 2;
                int c = kg >> 3, off = kg & 7;
                float4 v = *(const float4*)(Af + (size_t)(m0 + m) * K + k0 + kg);
                u16 h0 = f2bf(v.x), h1 = f2bf(v.y), h2 = f2bf(v.z), h3 = f2bf(v.w);
                ushort4 hv = {h0, h1, h2, h3};
                ushort4 lv = {f2bf(v.x - bf2f(h0)), f2bf(v.y - bf2f(h1)),
                              f2bf(v.z - bf2f(h2)), f2bf(v.w - bf2f(h3))};
                *(ushort4*)&sAh[c * CHS + m * 8 + off] = hv;
                *(ushort4*)&sAl[c * CHS + m * 8 + off] = lv;
            }
        } else {
            #pragma unroll
            for (int s = 0; s < 4; ++s) {
                int slot = tid + s * 256;
                int m = slot >> 3, ke = (slot & 7) << 2;   // 4 elems per uint4
                int c = ke >> 3, off = ke & 7;
                uint4 u = *(const uint4*)(Apk + (size_t)(m0 + m) * K + k0 + ke);
                ushort4 hv = {(u16)(u.x & 0xffff), (u16)(u.y & 0xffff),
                              (u16)(u.z & 0xffff), (u16)(u.w & 0xffff)};
                ushort4 lv = {(u16)(u.x >> 16), (u16)(u.y >> 16),
                              (u16)(u.z >> 16), (u16)(u.w >> 16)};
                *(ushort4*)&sAh[c * CHS + m * 8 + off] = hv;
                *(ushort4*)&sAl[c * CHS + m * 8 + off] = lv;
            }
        }
        // B planes [N,K] bf16 -> LDS (8 k-elems per uint4 = exactly one chunk row)
        #pragma unroll
        for (int s = 0; s < 4; ++s) {
            int slot = tid + s * 256;                 // 1024 slots, 512 per plane
            int n = (slot & 511) >> 2, ku = slot & 3; // ku = chunk
            const u16* src = (slot < 512) ? Bhi : Blo;
            u16* dst = (slot < 512) ? sBh : sBl;
            uint4 u = *(const uint4*)(src + (size_t)(n0 + n) * K + k0 + ku * 8);
            *(uint4*)&dst[ku * CHS + n * 8] = u;
        }
        __syncthreads();

        short8 ah[4], al[4], bh[4], bl[4];
        const int kc = quad * CHS;
        #pragma unroll
        for (int i = 0; i < 4; ++i) {
            int ar = wm + i * 16 + l15;
            int br = wn + i * 16 + l15;
            ah[i] = *(const short8*)&sAh[kc + ar * 8];
            al[i] = *(const short8*)&sAl[kc + ar * 8];
            bh[i] = *(const short8*)&sBh[kc + br * 8];
            bl[i] = *(const short8*)&sBl[kc + br * 8];
        }
        #pragma unroll
        for (int i = 0; i < 4; ++i)
            #pragma unroll
            for (int j = 0; j < 4; ++j) {
                acc[i][j] = __builtin_amdgcn_mfma_f32_16x16x32_bf16(ah[i], bh[j], acc[i][j], 0, 0, 0);
                acc[i][j] = __builtin_amdgcn_mfma_f32_16x16x32_bf16(ah[i], bl[j], acc[i][j], 0, 0, 0);
                acc[i][j] = __builtin_amdgcn_mfma_f32_16x16x32_bf16(al[i], bh[j], acc[i][j], 0, 0, 0);
            }
    }

    // epilogue. C/D layout: col = n-tile + l15, row = m-tile + quad*4 + r
    if (EPI <= 1) {
        float bn[4];
        #pragma unroll
        for (int j = 0; j < 4; ++j) bn[j] = bias[n0 + wn + j * 16 + l15];
        #pragma unroll
        for (int i = 0; i < 4; ++i)
            #pragma unroll
            for (int r = 0; r < 4; ++r) {
                int row = m0 + wm + i * 16 + quad * 4 + r;
                #pragma unroll
                for (int j = 0; j < 4; ++j) {
                    float v = acc[i][j][r] + bn[j];
                    if (EPI == 0) v = fmaxf(v, 0.f);
                    u16 h = f2bf(v); u16 l = f2bf(v - bf2f(h));
                    Opk[(size_t)row * N + n0 + wn + j * 16 + l15] = (u32)h | ((u32)l << 16);
                }
            }
    } else {
        float cs[4]; int cidx[4];
        #pragma unroll
        for (int j = 0; j < 4; ++j) {
            cidx[j] = n0 + wn + j * 16 + l15;
            cs[j] = bias[cidx[j]];
        }
        const int nparts = gridDim.x * 2;
        const int pslot  = bx * 2 + (w >> 1);   // distinct per wave-column!
        #pragma unroll
        for (int i = 0; i < 4; ++i)
            #pragma unroll
            for (int r = 0; r < 4; ++r) {
                int row = m0 + wm + i * 16 + quad * 4 + r;
                float d1 = 3.4e38f, d2 = 3.4e38f; int i1 = 0x7fffffff;
                #pragma unroll
                for (int j = 0; j < 4; ++j) {
                    float v = fmaf(-2.0f, acc[i][j][r], cs[j]);
                    if (v < d1) { d2 = d1; d1 = v; i1 = cidx[j]; }
                    else d2 = fminf(d2, v);
                }
                #pragma unroll
                for (int mm = 1; mm < 16; mm <<= 1) {
                    float od1 = __shfl_xor(d1, mm, 64);
                    float od2 = __shfl_xor(d2, mm, 64);
                    int   oi1 = __shfl_xor(i1, mm, 64);
                    if (od1 < d1 || (od1 == d1 && oi1 < i1)) { d2 = fminf(d1, od2); d1 = od1; i1 = oi1; }
                    else d2 = fminf(d2, od1);
                }
                if (l15 == 0) {
                    float4 o = {d1, d2, __int_as_float(i1), 0.f};
                    *(float4*)&Opart[((size_t)row * nparts + pslot) * 4] = o;
                }
            }
    }
}

// ---------------------------------------------------------------------------
// zsq from packed z
// ---------------------------------------------------------------------------
__global__ __launch_bounds__(256) void zsq_pk(
    const u32* __restrict__ Zpk, float* __restrict__ zsq)
{
    int tok = blockIdx.x * 4 + (threadIdx.x >> 6);
    int lane = threadIdx.x & 63;
    uint4 u = *(const uint4*)(Zpk + (size_t)tok * CBD + lane * 4);
    float z0 = bf2f((u16)(u.x & 0xffff)) + bf2f((u16)(u.x >> 16));
    float z1 = bf2f((u16)(u.y & 0xffff)) + bf2f((u16)(u.y >> 16));
    float z2 = bf2f((u16)(u.z & 0xffff)) + bf2f((u16)(u.z >> 16));
    float z3 = bf2f((u16)(u.w & 0xffff)) + bf2f((u16)(u.w >> 16));
    float s = z0 * z0 + z1 * z1 + z2 * z2 + z3 * z3;
    #pragma unroll
    for (int off = 32; off; off >>= 1) s += __shfl_down(s, off, 64);
    if (!lane) zsq[tok] = s;
}

// ---------------------------------------------------------------------------
// combine per-slot top2 partials (8 per token) -> idx, flags, commit sum
// threshold 0.01: bf16x3 dist error RMS ~2e-4, extreme tail ~2e-3 -> >=5x
// margin; near-ties (<1e-5) remain flagged under both 0.05 and 0.01 and are
// resolved by the byte-identical exact path.
// ---------------------------------------------------------------------------
__global__ __launch_bounds__(256) void vq_reduce(
    const float* __restrict__ part, const float* __restrict__ zsq,
    float* __restrict__ out_idx, int* __restrict__ idx_i,
    int* __restrict__ cnt, float* __restrict__ accum, int* __restrict__ flags)
{
    int tok = blockIdx.x * 256 + threadIdx.x;
    float d1 = 3.4e38f, d2 = 3.4e38f; int i1 = 0x7fffffff;
    #pragma unroll
    for (int nb = 0; nb < 8; ++nb) {
        float4 p = *(const float4*)&part[((size_t)tok * 8 + nb) * 4];
        float pd1 = p.x, pd2 = p.y; int pi1 = __float_as_int(p.z);
        if (pd1 < d1 || (pd1 == d1 && pi1 < i1)) { d2 = fminf(d1, pd2); d1 = pd1; i1 = pi1; }
        else d2 = fminf(d2, pd1);
    }
    out_idx[tok] = (float)i1;
    idx_i[tok] = i1;
    if (d2 - d1 < 0.01f) {
        int p = atomicAdd(cnt, 1);
        if (p >= 0 && p < NTOK) flags[p] = tok;
    }
    float c = zsq[tok] + d1;      // ||z||^2 + c_sq - 2 dot = ||z - q||^2
    __shared__ float red[256];
    red[threadIdx.x] = c; __syncthreads();
    for (int s = 128; s; s >>= 1) { if (threadIdx.x < s) red[threadIdx.x] += red[threadIdx.x + s]; __syncthreads(); }
    if (!threadIdx.x) atomicAdd(accum, red[0]);
}

// ---------------------------------------------------------------------------
// exact fp32 recompute of argmin for near-tie tokens (round-2 structure:
// 8 tokens/iter, register-tiled GEMMs, verbatim dist/argmin tie-breaks)
// ---------------------------------------------------------------------------
__global__ __launch_bounds__(256) void fixup(
    const int* __restrict__ cnt, const int* __restrict__ flags,
    const float* __restrict__ x, const float* __restrict__ W1, const float* __restrict__ b1,
    const float* __restrict__ W2, const float* __restrict__ b2,
    const float* __restrict__ cb, const float* __restrict__ csq,
    int* __restrict__ idx_i, float* __restrict__ out_idx)
{
    __shared__ float xs[8][IND];   // 24 KB
    __shared__ float hs[8][HID];   // 16 KB
    __shared__ float zs[8][CBD];   //  8 KB
    __shared__ float bd_s[4][8];
    __shared__ int   bi_s[4][8];
    __shared__ int   tok_s[8];

    int n = cnt[0]; if (n > NTOK) n = NTOK; if (n < 0) n = 0;
    const int t = threadIdx.x;
    const int nb = (n + 7) >> 3;

    for (int ib = blockIdx.x; ib < nb; ib += gridDim.x) {
        const int base = ib * 8;
        if (t < 8) {
            int fi = base + t; if (fi > n - 1) fi = n - 1;
            tok_s[t] = flags[fi];
        }
        __syncthreads();

        // stage 8 x-rows: 1536 float4, 6 per thread
        #pragma unroll
        for (int s = 0; s < 6; ++s) {
            int slot = t + s * 256;
            int tt = slot / 192, c4 = slot - tt * 192;
            *(float4*)&xs[tt][c4 * 4] =
                *(const float4*)(x + (size_t)tok_s[tt] * IND + c4 * 4);
        }
        __syncthreads();

        // h = relu(x @ W1 + b1): thread owns 4 tokens (tg) x 4 cols (j0..j0+3)
        {
            const int tg = t >> 7;          // 0..1 -> tokens tg*4..tg*4+3
            const int j0 = (t & 127) * 4;   // 4 consecutive cols
            float a[4][4];
            float4 bb = *(const float4*)(b1 + j0);
            #pragma unroll
            for (int ti = 0; ti < 4; ++ti) {
                a[ti][0] = bb.x; a[ti][1] = bb.y; a[ti][2] = bb.z; a[ti][3] = bb.w;
            }
            for (int k4 = 0; k4 < IND / 4; ++k4) {
                float4 xv[4];
                #pragma unroll
                for (int ti = 0; ti < 4; ++ti)
                    xv[ti] = *(const float4*)&xs[tg * 4 + ti][k4 * 4];
                #pragma unroll
                for (int kk = 0; kk < 4; ++kk) {
                    float4 wv = *(const float4*)(W1 + (size_t)(k4 * 4 + kk) * HID + j0);
                    #pragma unroll
                    for (int ti = 0; ti < 4; ++ti) {
                        float xk = (kk == 0) ? xv[ti].x : (kk == 1) ? xv[ti].y
                                 : (kk == 2) ? xv[ti].z : xv[ti].w;
                        a[ti][0] = fmaf(xk, wv.x, a[ti][0]);
                        a[ti][1] = fmaf(xk, wv.y, a[ti][1]);
                        a[ti][2] = fmaf(xk, wv.z, a[ti][2]);
                        a[ti][3] = fmaf(xk, wv.w, a[ti][3]);
                    }
                }
            }
            #pragma unroll
            for (int ti = 0; ti < 4; ++ti) {
                float4 o = {fmaxf(a[ti][0], 0.f), fmaxf(a[ti][1], 0.f),
                            fmaxf(a[ti][2], 0.f), fmaxf(a[ti][3], 0.f)};
                *(float4*)&hs[tg * 4 + ti][j0] = o;
            }
        }
        __syncthreads();

        // z = h @ W2 + b2: thread owns 2 tokens (tg) x 4 cols (c0..c0+3)
        {
            const int tg = t >> 6;          // 0..3 -> tokens tg*2, tg*2+1
            const int c0 = (t & 63) * 4;
            float az[2][4];
            float4 bz = *(const float4*)(b2 + c0);
            #pragma unroll
            for (int ti = 0; ti < 2; ++ti) {
                az[ti][0] = bz.x; az[ti][1] = bz.y; az[ti][2] = bz.z; az[ti][3] = bz.w;
            }
            for (int k4 = 0; k4 < HID / 4; ++k4) {
                float4 hv[2];
                #pragma unroll
                for (int ti = 0; ti < 2; ++ti)
                    hv[ti] = *(const float4*)&hs[tg * 2 + ti][k4 * 4];
                #pragma unroll
                for (int kk = 0; kk < 4; ++kk) {
                    float4 wv = *(const float4*)(W2 + (size_t)(k4 * 4 + kk) * CBD + c0);
                    #pragma unroll
                    for (int ti = 0; ti < 2; ++ti) {
                        float hk = (kk == 0) ? hv[ti].x : (kk == 1) ? hv[ti].y
                                 : (kk == 2) ? hv[ti].z : hv[ti].w;
                        az[ti][0] = fmaf(hk, wv.x, az[ti][0]);
                        az[ti][1] = fmaf(hk, wv.y, az[ti][1]);
                        az[ti][2] = fmaf(hk, wv.z, az[ti][2]);
                        az[ti][3] = fmaf(hk, wv.w, az[ti][3]);
                    }
                }
            }
            #pragma unroll
            for (int ti = 0; ti < 2; ++ti) {
                float4 o = {az[ti][0], az[ti][1], az[ti][2], az[ti][3]};
                *(float4*)&zs[tg * 2 + ti][c0] = o;
            }
        }
        __syncthreads();

        // dists + argmin: wave wv owns codes [wv*128, wv*128+128)  (verbatim)
        {
            const int wv = t >> 6, l = t & 63;
            float4 zv[8];
            #pragma unroll
            for (int tt = 0; tt < 8; ++tt) zv[tt] = *(const float4*)&zs[tt][l * 4];
            float bd[8]; int bi[8];
            #pragma unroll
            for (int tt = 0; tt < 8; ++tt) { bd[tt] = 3.4e38f; bi[tt] = 0x7fffffff; }
            for (int cc = 0; cc < 128; ++cc) {
                int c = wv * 128 + cc;
                float4 cv = *(const float4*)(cb + (size_t)c * CBD + l * 4);
                float cs = csq[c];
                #pragma unroll
                for (int tt = 0; tt < 8; ++tt) {
                    float p = zv[tt].x * cv.x + zv[tt].y * cv.y + zv[tt].z * cv.z + zv[tt].w * cv.w;
                    #pragma unroll
                    for (int mm = 32; mm; mm >>= 1) p += __shfl_xor(p, mm, 64);
                    float d = cs - 2.f * p;
                    if (d < bd[tt]) { bd[tt] = d; bi[tt] = c; }  // ascending c -> keeps first
                }
            }
            if (l == 0) {
                #pragma unroll
                for (int tt = 0; tt < 8; ++tt) { bd_s[wv][tt] = bd[tt]; bi_s[wv][tt] = bi[tt]; }
            }
        }
        __syncthreads();

        if (t < 8) {
            const int tt = t;
            float d = bd_s[0][tt]; int i = bi_s[0][tt];
            #pragma unroll
            for (int wv = 1; wv < 4; ++wv) {
                float od = bd_s[wv][tt]; int oi = bi_s[wv][tt];
                if (od < d || (od == d && oi < i)) { d = od; i = oi; }
            }
            if (base + tt < n) {
                int tok = tok_s[tt];
                idx_i[tok] = i; out_idx[tok] = (float)i;
            }
        }
        __syncthreads();
    }
}

// ---------------------------------------------------------------------------
// ReconTable = decoder(codebook): one block per code
// ---------------------------------------------------------------------------
__global__ __launch_bounds__(256) void table_pre(
    const float* __restrict__ cb, const float* __restrict__ W3,
    const float* __restrict__ b3, const float* __restrict__ W4,
    const float* __restrict__ b4, float* __restrict__ table)
{
    __shared__ float crow[CBD];
    __shared__ float h2[HID];
    const int c = blockIdx.x;
    const int t = threadIdx.x;
    crow[t] = cb[(size_t)c * CBD + t];
    __syncthreads();
    #pragma unroll
    for (int s = 0; s < 2; ++s) {
        int j = t + s * 256;
        float acc = b3[j];
        for (int k = 0; k < CBD; ++k) acc = fmaf(crow[k], W3[(size_t)k * HID + j], acc);
        h2[j] = fmaxf(acc, 0.f);
    }
    __syncthreads();
    #pragma unroll
    for (int s = 0; s < 3; ++s) {
        int j = t + s * 256;
        float acc = b4[j];
        for (int k = 0; k < HID; ++k) acc = fmaf(h2[k], W4[(size_t)k * IND + j], acc);
        table[(size_t)c * IND + j] = acc;
    }
}

// ---------------------------------------------------------------------------
// recon gather
// ---------------------------------------------------------------------------
__global__ __launch_bounds__(256) void gather_kernel(
    const int* __restrict__ idx, const float* __restrict__ table,
    float* __restrict__ out)
{
    unsigned i = blockIdx.x * 256u + threadIdx.x;   // float4 index, total NTOK*192
    unsigned tok = i / 192u;
    unsigned c = i - tok * 192u;
    int id = idx[tok];
    ((float4*)out)[i] = ((const float4*)table)[(size_t)id * 192 + c];
}

__global__ void finalize_kernel(const float* __restrict__ accum,
                                float* __restrict__ out_loss)
{
    out_loss[0] = accum[0] * (1.0f / 16777216.0f);   // mean over NTOK*CBD
}

// ---------------------------------------------------------------------------
extern "C" void kernel_launch(void* const* d_in, const int* in_sizes, int n_in,
                              void* d_out, int out_size, void* d_ws, size_t ws_size,
                              hipStream_t stream) {
    const float* x  = (const float*)d_in[0];
    const float* W1 = (const float*)d_in[1];
    const float* b1 = (const float*)d_in[2];
    const float* W2 = (const float*)d_in[3];
    const float* b2 = (const float*)d_in[4];
    const float* cb = (const float*)d_in[5];
    const float* W3 = (const float*)d_in[6];
    const float* b3 = (const float*)d_in[7];
    const float* W4 = (const float*)d_in[8];
    const float* b4 = (const float*)d_in[9];

    char* ws = (char*)d_ws;
    u32*  Hpk   = (u32*)(ws + OFF_H);
    u32*  Zpk   = (u32*)(ws + OFF_Z);
    u16*  W1h   = (u16*)(ws + OFF_W1H);
    u16*  W1l   = (u16*)(ws + OFF_W1L);
    u16*  W2h   = (u16*)(ws + OFF_W2H);
    u16*  W2l   = (u16*)(ws + OFF_W2L);
    u16*  CBh   = (u16*)(ws + OFF_CBH);
    u16*  CBl   = (u16*)(ws + OFF_CBL);
    float* csq  = (float*)(ws + OFF_CSQ);
    float* part = (float*)(ws + OFF_PART);
    float* table = (float*)(ws + OFF_TABLE);
    float* zsq  = (float*)(ws + OFF_ZSQ);
    int*   idx_i = (int*)(ws + OFF_IDX);
    int*   flags = (int*)(ws + OFF_FLAGS);
    int*   cnt   = (int*)(ws + OFF_CNT);
    float* accum = (float*)(ws + OFF_CNT + 4);

    float* out      = (float*)d_out;
    float* out_idx  = out + OUT_IDX_OFF;
    float* out_loss = out + OUT_LOSS_OFF;

    cbsplit<<<CBS, 256, 0, stream>>>(cb, CBh, CBl, csq);
    wsplit<<<HID, 256, 0, stream>>>(W1, W1h, W1l, IND, HID);   // W1T [512][768]
    wsplit<<<CBD, 256, 0, stream>>>(W2, W2h, W2l, HID, CBD);   // W2T [256][512]

    // h = relu(x @ W1 + b1) -> packed planes
    gemm3<0, 0><<<dim3(HID / 128, NTOK / 128), 256, 0, stream>>>(
        x, (const u32*)nullptr, W1h, W1l, b1, Hpk, (float*)nullptr, NTOK, HID, IND);
    // z = h @ W2 + b2 -> packed planes
    gemm3<1, 1><<<dim3(CBD / 128, NTOK / 128), 256, 0, stream>>>(
        (const float*)nullptr, Hpk, W2h, W2l, b2, Zpk, (float*)nullptr, NTOK, CBD, HID);

    // H region is dead from here on; zero cnt/accum AFTER GEMM1's Hpk writes
    // (round-2 bug: zeroing first got clobbered -> garbage cnt -> OOB flags write)
    hipMemsetAsync(cnt, 0, 8, stream);

    zsq_pk<<<NTOK / 4, 256, 0, stream>>>(Zpk, zsq);

    // dists top-2 partials: dist = c_sq - 2 * (z . c)
    gemm3<1, 2><<<dim3(CBS / 128, NTOK / 128), 256, 0, stream>>>(
        (const float*)nullptr, Zpk, CBh, CBl, csq, (u32*)nullptr, part, NTOK, CBS, CBD);

    table_pre<<<CBS, 256, 0, stream>>>(cb, W3, b3, W4, b4, table);

    vq_reduce<<<NTOK / 256, 256, 0, stream>>>(part, zsq, out_idx, idx_i, cnt, accum, flags);

    // batched fixup: 8 tokens/block-iter, grid-stride. 48KB LDS -> 3 blocks/CU.
    fixup<<<1024, 256, 0, stream>>>(cnt, flags, x, W1, b1, W2, b2, cb, csq, idx_i, out_idx);

    gather_kernel<<<(NTOK * (IND / 4)) / 256, 256, 0, stream>>>(idx_i, table, out);

    finalize_kernel<<<1, 1, 0, stream>>>(accum, out_loss);
}